// Round 4
// baseline (4066.239 us; speedup 1.0000x reference)
//
#include <hip/hip_runtime.h>

#define SEQ 2048
#define D 128

// ---------------------------------------------------------------------------
// Kernel 1: per-step J-independent quantities (fully parallel), UNNORMALIZED:
//   alpha_i = k_s . q_i      (i <= s)
//   kqq[s]  = sum alpha_i^2          = l * (k^T Sqq_l k)
//   sl[s]   = sum alpha_i (v_s.v_i)  = l * (k^T Sqv_l v)
//   vv[s]   = v_s . v_s
//   U[s][c] = sum_i q_i[c] alpha_i   = l * (Sqq_l k)[c]
//   invl[s] = 1.0 / l   (fp64, for cost rescale)
// ---------------------------------------------------------------------------
__global__ __launch_bounds__(256) void precompute_kernel(
    const float* __restrict__ q, const float* __restrict__ k, const float* __restrict__ v,
    float* __restrict__ U, float* __restrict__ sl, float* __restrict__ kqq,
    float* __restrict__ vv, double* __restrict__ invl)
{
    const int s = blockIdx.x;
    const int tid = threadIdx.x;

    __shared__ float ks[D];
    __shared__ float vs[D];
    __shared__ float alpha[SEQ];
    __shared__ float red[8];
    __shared__ float upart[256];

    if (tid < D) ks[tid] = k[s * D + tid];
    else if (tid < 2 * D) vs[tid - D] = v[s * D + (tid - D)];
    __syncthreads();

    float p_a2 = 0.f, p_ab = 0.f;
    for (int i = tid; i <= s; i += 256) {
        const float4* qr = (const float4*)(q + (size_t)i * D);
        const float4* vr = (const float4*)(v + (size_t)i * D);
        float a = 0.f, b = 0.f;
#pragma unroll
        for (int j = 0; j < D / 4; ++j) {
            float4 q4 = qr[j];
            float4 v4 = vr[j];
            a += q4.x * ks[4 * j + 0] + q4.y * ks[4 * j + 1] + q4.z * ks[4 * j + 2] + q4.w * ks[4 * j + 3];
            b += v4.x * vs[4 * j + 0] + v4.y * vs[4 * j + 1] + v4.z * vs[4 * j + 2] + v4.w * vs[4 * j + 3];
        }
        alpha[i] = a;
        p_a2 += a * a;
        p_ab += a * b;
        if (i == s) vv[s] = b;  // v_s . v_s
    }
#pragma unroll
    for (int off = 1; off < 64; off <<= 1) {
        p_a2 += __shfl_xor(p_a2, off);
        p_ab += __shfl_xor(p_ab, off);
    }
    const int wid = tid >> 6;
    if ((tid & 63) == 0) { red[wid] = p_a2; red[4 + wid] = p_ab; }
    __syncthreads();  // also makes alpha[] visible to everyone
    if (tid == 0) {
        kqq[s] = red[0] + red[1] + red[2] + red[3];
        sl[s]  = red[4] + red[5] + red[6] + red[7];
        invl[s] = 1.0 / (double)(s + 1);
    }

    // pass 2: U[s][c] = sum_i q[i][c] * alpha[i], split i over 2 halves
    const int c = tid & (D - 1);
    const int h = tid >> 7;  // 0 or 1
    float acc = 0.f;
    for (int i = h; i <= s; i += 2) acc += q[(size_t)i * D + c] * alpha[i];
    upart[tid] = acc;
    __syncthreads();
    if (tid < D) U[(size_t)s * D + tid] = upart[tid] + upart[tid + D];
}

// ---------------------------------------------------------------------------
// Kernel 2: sequential scan, one 256-thread workgroup (4 waves, 1 per SIMD).
// ROUND-4 FIX: round 3 still spilled (VGPR=80, FETCH_SIZE=2.6GB) because
// `*(float4*)&jr[4*j]` address-takes the local array -> alloca in scratch.
// J slice now lives in 16 NAMED float4 registers (jr0..jr15, macro-expanded,
// never address-taken) -> guaranteed SROA promotion. Same for kk0..kk15.
// Everything else identical to round 3.
// ---------------------------------------------------------------------------

#define REP16(F) F(0) F(1) F(2) F(3) F(4) F(5) F(6) F(7) \
                 F(8) F(9) F(10) F(11) F(12) F(13) F(14) F(15)

__global__ __launch_bounds__(256, 1) void scan_kernel(
    const float* __restrict__ q, const float* __restrict__ k, const float* __restrict__ v,
    const float* __restrict__ U, const float* __restrict__ sl_arr,
    const float* __restrict__ kqq_arr, const float* __restrict__ vv_arr,
    const double* __restrict__ invl_arr,
    float* __restrict__ out)  // [0,2048) costs | [2048,4096) updated | [4096,...) J
{
    const int tid  = threadIdx.x;
    const int lane = tid & 63;
    const int w  = __builtin_amdgcn_readfirstlane(tid >> 6);  // 0..3, uniform
    const int g  = w & 1;          // column half
    const int rb = w >> 1;         // row block
    const int r  = rb * 64 + lane; // my row
    const int c0 = g * 64;         // my column base

    // J slice: 16 named float4 registers (never address-taken)
#define DECLJ(i) float4 jr##i = make_float4(0.f, 0.f, 0.f, 0.f);
    REP16(DECLJ)
#undef DECLJ

    __shared__ float  sbuf[3][2][D];   // [phase][q,u][128] staging ring
    __shared__ float2 part[4][64];     // per-wave (pq, pu) partials
    __shared__ float  wred[4][2];      // per-wave reduced scalars

    // staging roles: threads 0-127 stage q-row element, 128-255 stage u-row
    const bool roleA = tid < 128;
    const int  sidx  = roleA ? tid : tid - 128;

    // ---- prologue: stage steps 0,1 into phases 0,1; regs hold step 2 ----
    for (int t = 0; t < 2; ++t) {
        if (roleA) sbuf[t][0][sidx] = q[(size_t)t * D + sidx];
        else       sbuf[t][1][sidx] = U[(size_t)t * D + sidx];
    }
    float gstage = roleA ? q[(size_t)2 * D + sidx] : U[(size_t)2 * D + sidx];
    float vcur = v[r], v1 = v[(size_t)1 * D + r], v2 = v[(size_t)2 * D + r];
    float  slc = sl_arr[0], kqc = kqq_arr[0], vvc = vv_arr[0];
    double invc = invl_arr[0];
    __syncthreads();

    double SJ = 0.0, AJJ = 0.0, trSvv = 0.0;

    for (int s = 0; s < SEQ; ++s) {
        const int p  = s % 3;
        const int pw = (s + 2) % 3;  // phase being written (data for step s+2)

        // ---- A: dots over my 64 columns (LDS broadcast reads) ----
        const float4* q4 = (const float4*)&sbuf[p][0][c0];
        const float4* u4 = (const float4*)&sbuf[p][1][c0];
        float pq0 = 0.f, pq1 = 0.f, pq2 = 0.f, pq3 = 0.f;
        float pu0 = 0.f, pu1 = 0.f, pu2 = 0.f, pu3 = 0.f;
#define DOTSTEP(i) { const float4 a = q4[i]; const float4 b = u4[i];          \
        pq0 = fmaf(jr##i.x, a.x, pq0); pq1 = fmaf(jr##i.y, a.y, pq1);         \
        pq2 = fmaf(jr##i.z, a.z, pq2); pq3 = fmaf(jr##i.w, a.w, pq3);         \
        pu0 = fmaf(jr##i.x, b.x, pu0); pu1 = fmaf(jr##i.y, b.y, pu1);         \
        pu2 = fmaf(jr##i.z, b.z, pu2); pu3 = fmaf(jr##i.w, b.w, pu3); }
        REP16(DOTSTEP)
#undef DOTSTEP
        float pq = (pq0 + pq1) + (pq2 + pq3);
        float pu = (pu0 + pu1) + (pu2 + pu3);

        // ---- B: write partials ----
        part[w][lane] = make_float2(pq, pu);

        // ---- F: stage (s+2) data (regs loaded 1 iteration ago) ----
        if (roleA) sbuf[pw][0][sidx] = gstage;
        else       sbuf[pw][1][sidx] = gstage;

        // ---- C: issue global loads: q/u for s+3, v for s+3, scalars s+1 ----
        const int t3 = (s + 3 < SEQ) ? s + 3 : SEQ - 1;
        const int t1 = (s + 1 < SEQ) ? s + 1 : SEQ - 1;
        gstage = roleA ? q[(size_t)t3 * D + sidx] : U[(size_t)t3 * D + sidx];
        const float vnew = v[(size_t)t3 * D + r];
        const float  sln = sl_arr[t1], kqn = kqq_arr[t1], vvn = vv_arr[t1];
        const double invn = invl_arr[t1];

        __syncthreads();  // B1

        // ---- E: combine partner wave (same rows, other cols) + reduce ----
        {
            float2 o = part[w ^ 1][lane];
            pq += o.x;
            pu += o.y;
        }
        float x0, x1 = 0.f;
        if (g == 0) {
            x0 = vcur * pq;          // -> v^T J q
            x1 = pq * pq;            // -> |J q|^2
#pragma unroll
            for (int off = 1; off < 64; off <<= 1) {
                x0 += __shfl_xor(x0, off);
                x1 += __shfl_xor(x1, off);
            }
        } else {
            x0 = vcur * pu;          // -> v^T J u  (A_Jl)
#pragma unroll
            for (int off = 1; off < 64; off <<= 1) x0 += __shfl_xor(x0, off);
        }
        if (lane == 0) { wred[w][0] = x0; wred[w][1] = x1; }

        __syncthreads();  // B2

        // ---- H: k row load (named regs; latency hidden by fp64 chain) ----
        const float4* k4 = (const float4*)(k + (size_t)s * D + c0);
#define LOADK(i) const float4 kk##i = k4[i];
        REP16(LOADK)
#undef LOADK

        const double Jqv = (double)wred[0][0] + (double)wred[2][0];
        const double Jq2 = (double)wred[0][1] + (double)wred[2][1];
        const double AJl = (double)wred[1][0] + (double)wred[3][0];

        // ---- redundant fp64 decision chain (identical on all threads) ----
        trSvv += (double)vvc;
        SJ    += Jqv;
        AJJ   += Jq2;
        const double s_l  = (double)slc;
        const double A_ll = (double)vvc * (double)kqc;
        const bool first = (s == 0);
        const double AJJ_s  = (first || AJJ == 0.0)  ? 1.0 : AJJ;   // > 0 always
        const double A_ll_s = (first || A_ll == 0.0) ? 1.0 : A_ll;
        const double denom   = AJJ * A_ll - AJl * AJl;
        const double denom_s = (first || denom == 0.0) ? 1.0 : denom;
        const double rden = 1.0 / denom_s;
        const double wf = (A_ll * SJ - AJl * s_l) * rden;
        const double wi = (AJJ * s_l - AJl * SJ) * rden;
        double wf_c, wi_c;
        if (wi <= 0.0)      { wf_c = SJ / AJJ_s;  wi_c = 0.0; }
        else if (wf <= 0.0) { wf_c = 0.0;         wi_c = s_l / A_ll_s; }
        else                { wf_c = wf;          wi_c = wi; }
        const bool do_update = (s_l * AJJ_s - AJl * SJ) > 0.0;  // margin * AJJ_s

        int mode;
        if (first) {
            mode = 2;
            SJ  = s_l;    // tr(vk^T Sqv') = k^T Sqv' v
            AJJ = A_ll;   // (v.v)(k^T Sqq' k)
        } else if (do_update) {
            mode = 1;
            const double nSJ = wf_c * SJ + wi_c * s_l;
            AJJ = wf_c * wf_c * AJJ + 2.0 * wf_c * wi_c * AJl + wi_c * wi_c * A_ll;
            SJ = nSJ;
        } else {
            mode = 0;
        }

        if (tid == 0) {
            out[s] = (float)((0.5 * trSvv - SJ + 0.5 * AJJ) * invc);
            out[SEQ + s] = (mode != 0) ? 1.f : 0.f;
        }

        // ---- I: J update (wave-uniform branch; pure register ops) ----
        if (mode == 2) {
#define SETJ(i) { jr##i.x = vcur * kk##i.x; jr##i.y = vcur * kk##i.y;          \
                  jr##i.z = vcur * kk##i.z; jr##i.w = vcur * kk##i.w; }
            REP16(SETJ)
#undef SETJ
        } else if (mode == 1) {
            const float wff = (float)wf_c;
            const float wvr = (float)wi_c * vcur;
#define UPDJ(i) { jr##i.x = fmaf(jr##i.x, wff, wvr * kk##i.x);                 \
                  jr##i.y = fmaf(jr##i.y, wff, wvr * kk##i.y);                 \
                  jr##i.z = fmaf(jr##i.z, wff, wvr * kk##i.z);                 \
                  jr##i.w = fmaf(jr##i.w, wff, wvr * kk##i.w); }
            REP16(UPDJ)
#undef UPDJ
        }

        // ---- shifts ----
        vcur = v1; v1 = v2; v2 = vnew;
        slc = sln; kqc = kqn; vvc = vvn; invc = invn;
    }

    // final J (row-major [d_v][d_k]) — float4 stores to global
    float* jbase = out + 2 * SEQ + (size_t)r * D + c0;
#define STJ(i) *(float4*)(jbase + 4 * i) = jr##i;
    REP16(STJ)
#undef STJ
}

extern "C" void kernel_launch(void* const* d_in, const int* in_sizes, int n_in,
                              void* d_out, int out_size, void* d_ws, size_t ws_size,
                              hipStream_t stream) {
    (void)in_sizes; (void)n_in; (void)out_size; (void)ws_size;
    const float* q = (const float*)d_in[0];
    const float* k = (const float*)d_in[1];
    const float* v = (const float*)d_in[2];
    float* out = (float*)d_out;

    float* U    = (float*)d_ws;             // SEQ*D floats (1 MB)
    float* sl   = U + (size_t)SEQ * D;      // SEQ
    float* kqq  = sl + SEQ;                 // SEQ
    float* vv   = kqq + SEQ;                // SEQ
    double* invl = (double*)(vv + SEQ);     // SEQ doubles (8B-aligned)

    precompute_kernel<<<SEQ, 256, 0, stream>>>(q, k, v, U, sl, kqq, vv, invl);
    scan_kernel<<<1, 256, 0, stream>>>(q, k, v, U, sl, kqq, vv, invl, out);
}

// Round 5
// 3984.520 us; speedup vs baseline: 1.0205x; 1.0205x over previous
//
#include <hip/hip_runtime.h>

#define SEQ 2048
#define D 128

// ---------------------------------------------------------------------------
// Kernel 1: per-step J-independent quantities (fully parallel), UNNORMALIZED:
//   alpha_i = k_s . q_i      (i <= s)
//   kqq[s]  = sum alpha_i^2          = l * (k^T Sqq_l k)
//   sl[s]   = sum alpha_i (v_s.v_i)  = l * (k^T Sqv_l v)
//   vv[s]   = v_s . v_s
//   U[s][c] = sum_i q_i[c] alpha_i   = l * (Sqq_l k)[c]
//   invl[s] = 1.0 / l   (fp64, for cost rescale)
// ---------------------------------------------------------------------------
__global__ __launch_bounds__(256) void precompute_kernel(
    const float* __restrict__ q, const float* __restrict__ k, const float* __restrict__ v,
    float* __restrict__ U, float* __restrict__ sl, float* __restrict__ kqq,
    float* __restrict__ vv, double* __restrict__ invl)
{
    const int s = blockIdx.x;
    const int tid = threadIdx.x;

    __shared__ float ks[D];
    __shared__ float vs[D];
    __shared__ float alpha[SEQ];
    __shared__ float red[8];
    __shared__ float upart[256];

    if (tid < D) ks[tid] = k[s * D + tid];
    else if (tid < 2 * D) vs[tid - D] = v[s * D + (tid - D)];
    __syncthreads();

    float p_a2 = 0.f, p_ab = 0.f;
    for (int i = tid; i <= s; i += 256) {
        const float4* qr = (const float4*)(q + (size_t)i * D);
        const float4* vr = (const float4*)(v + (size_t)i * D);
        float a = 0.f, b = 0.f;
#pragma unroll
        for (int j = 0; j < D / 4; ++j) {
            float4 q4 = qr[j];
            float4 v4 = vr[j];
            a += q4.x * ks[4 * j + 0] + q4.y * ks[4 * j + 1] + q4.z * ks[4 * j + 2] + q4.w * ks[4 * j + 3];
            b += v4.x * vs[4 * j + 0] + v4.y * vs[4 * j + 1] + v4.z * vs[4 * j + 2] + v4.w * vs[4 * j + 3];
        }
        alpha[i] = a;
        p_a2 += a * a;
        p_ab += a * b;
        if (i == s) vv[s] = b;  // v_s . v_s
    }
#pragma unroll
    for (int off = 1; off < 64; off <<= 1) {
        p_a2 += __shfl_xor(p_a2, off);
        p_ab += __shfl_xor(p_ab, off);
    }
    const int wid = tid >> 6;
    if ((tid & 63) == 0) { red[wid] = p_a2; red[4 + wid] = p_ab; }
    __syncthreads();  // also makes alpha[] visible to everyone
    if (tid == 0) {
        kqq[s] = red[0] + red[1] + red[2] + red[3];
        sl[s]  = red[4] + red[5] + red[6] + red[7];
        invl[s] = 1.0 / (double)(s + 1);
    }

    // pass 2: U[s][c] = sum_i q[i][c] * alpha[i], split i over 2 halves
    const int c = tid & (D - 1);
    const int h = tid >> 7;  // 0 or 1
    float acc = 0.f;
    for (int i = h; i <= s; i += 2) acc += q[(size_t)i * D + c] * alpha[i];
    upart[tid] = acc;
    __syncthreads();
    if (tid < D) U[(size_t)s * D + tid] = upart[tid] + upart[tid + D];
}

// ---------------------------------------------------------------------------
// Kernel 2: sequential scan, one 1024-thread workgroup (16 waves, 4/SIMD).
// ROUND-5: rounds 2-4 all spilled J to scratch (VGPR stuck at 80, FETCH
// 2.6-3.1 GB = scratch traffic). Fix: shrink per-thread J state to 16
// elements (4 float4) so peak pressure ~60 VGPR — below the allocator's
// observed ~80 ceiling. Thread (r = tid>>3, cg = tid&7) owns
// J[r][cg*16 .. cg*16+15]. Row dot combined via shfl_xor(1,2,4); the three
// step scalars reduced per-wave via shfl_xor(8,16,32) -> wred[16][3] ->
// fp64 decision chain on WAVE 0 ONLY (redundant over its 64 lanes),
// decisions broadcast through dec[4]. Still 2 barriers/step. q/u rows come
// from the 3-phase LDS staging ring (broadcast ds_reads, never resident in
// VGPRs); k row is loaded to transient regs pre-B1 (latency hidden by the
// chain); v element + per-step scalars register-prefetched.
// ---------------------------------------------------------------------------
__global__ __launch_bounds__(1024, 4) void scan_kernel(
    const float* __restrict__ q, const float* __restrict__ k, const float* __restrict__ v,
    const float* __restrict__ U, const float* __restrict__ sl_arr,
    const float* __restrict__ kqq_arr, const float* __restrict__ vv_arr,
    const double* __restrict__ invl_arr,
    float* __restrict__ out)  // [0,2048) costs | [2048,4096) updated | [4096,...) J
{
    const int tid  = threadIdx.x;
    const int lane = tid & 63;
    const int w    = __builtin_amdgcn_readfirstlane(tid >> 6);  // 0..15, uniform
    const int r    = tid >> 3;        // my row, 0..127
    const int cg   = tid & 7;         // col group
    const int c0   = cg * 16;         // my column base

    float4 jr0 = make_float4(0.f, 0.f, 0.f, 0.f);
    float4 jr1 = make_float4(0.f, 0.f, 0.f, 0.f);
    float4 jr2 = make_float4(0.f, 0.f, 0.f, 0.f);
    float4 jr3 = make_float4(0.f, 0.f, 0.f, 0.f);

    __shared__ float sbuf[3][2][D];   // [phase][q,u][128] staging ring
    __shared__ float wred[16][3];     // per-wave reduced scalars
    __shared__ float dec[4];          // wf_c, wi_c, mode

    // staging roles: threads 0-127 stage q-row, 128-255 stage u-row
    const bool stager = tid < 256;
    const int  which  = (tid >> 7) & 1;   // 0: q, 1: u
    const int  sidx   = tid & 127;

    // ---- prologue: stage steps 0,1 into phases 0,1; reg holds step 2 ----
    float gstage = 0.f;
    if (stager) {
        const float* src = which ? U : q;
        sbuf[0][which][sidx] = src[sidx];
        sbuf[1][which][sidx] = src[(size_t)D + sidx];
        gstage = src[(size_t)2 * D + sidx];
    }
    float vcur = v[r], v1 = v[(size_t)D + r], v2 = v[(size_t)2 * D + r];
    float  slc = sl_arr[0], kqc = kqq_arr[0], vvc = vv_arr[0];
    double invc = invl_arr[0];
    __syncthreads();

    double SJ = 0.0, AJJ = 0.0, trSvv = 0.0;   // live only on wave 0

    for (int s = 0; s < SEQ; ++s) {
        const int p  = s % 3;
        const int pw = (s + 2) % 3;  // phase being written (data for step s+2)

        // ---- K: issue k-row chunk loads for this step (used post-B2) ----
        const float4* k4 = (const float4*)(k + (size_t)s * D + c0);
        const float4 kk0 = k4[0], kk1 = k4[1], kk2 = k4[2], kk3 = k4[3];

        // ---- A: partial dots over my 16 columns (LDS broadcast reads) ----
        const float4* q4 = (const float4*)&sbuf[p][0][c0];
        const float4* u4 = (const float4*)&sbuf[p][1][c0];
        const float4 qa = q4[0], qb = q4[1], qc = q4[2], qd = q4[3];
        const float4 ua = u4[0], ub = u4[1], uc = u4[2], ud = u4[3];
        float pq = 0.f, pu = 0.f;
        pq = fmaf(jr0.x, qa.x, pq); pq = fmaf(jr0.y, qa.y, pq);
        pq = fmaf(jr0.z, qa.z, pq); pq = fmaf(jr0.w, qa.w, pq);
        pq = fmaf(jr1.x, qb.x, pq); pq = fmaf(jr1.y, qb.y, pq);
        pq = fmaf(jr1.z, qb.z, pq); pq = fmaf(jr1.w, qb.w, pq);
        pq = fmaf(jr2.x, qc.x, pq); pq = fmaf(jr2.y, qc.y, pq);
        pq = fmaf(jr2.z, qc.z, pq); pq = fmaf(jr2.w, qc.w, pq);
        pq = fmaf(jr3.x, qd.x, pq); pq = fmaf(jr3.y, qd.y, pq);
        pq = fmaf(jr3.z, qd.z, pq); pq = fmaf(jr3.w, qd.w, pq);
        pu = fmaf(jr0.x, ua.x, pu); pu = fmaf(jr0.y, ua.y, pu);
        pu = fmaf(jr0.z, ua.z, pu); pu = fmaf(jr0.w, ua.w, pu);
        pu = fmaf(jr1.x, ub.x, pu); pu = fmaf(jr1.y, ub.y, pu);
        pu = fmaf(jr1.z, ub.z, pu); pu = fmaf(jr1.w, ub.w, pu);
        pu = fmaf(jr2.x, uc.x, pu); pu = fmaf(jr2.y, uc.y, pu);
        pu = fmaf(jr2.z, uc.z, pu); pu = fmaf(jr2.w, uc.w, pu);
        pu = fmaf(jr3.x, ud.x, pu); pu = fmaf(jr3.y, ud.y, pu);
        pu = fmaf(jr3.z, ud.z, pu); pu = fmaf(jr3.w, ud.w, pu);

        // row combine: 8 lanes (cg 0..7) hold col-chunks of the same row
        pq += __shfl_xor(pq, 1); pu += __shfl_xor(pu, 1);
        pq += __shfl_xor(pq, 2); pu += __shfl_xor(pu, 2);
        pq += __shfl_xor(pq, 4); pu += __shfl_xor(pu, 4);
        // now pq = (Jq)[r], pu = (J^T? no: J u)[r] on all 8 lanes of row r

        // ---- F: stage (s+2) data (reg loaded 1 iteration ago) ----
        if (stager) sbuf[pw][which][sidx] = gstage;

        // ---- C: issue prefetches: q/u for s+3, v for s+3, scalars s+1 ----
        const int t3 = (s + 3 < SEQ) ? s + 3 : SEQ - 1;
        const int t1 = (s + 1 < SEQ) ? s + 1 : SEQ - 1;
        if (stager) gstage = (which ? U : q)[(size_t)t3 * D + sidx];
        const float vnew = v[(size_t)t3 * D + r];
        const float  sln = sl_arr[t1], kqn = kqq_arr[t1], vvn = vv_arr[t1];
        const double invn = invl_arr[t1];

        // ---- role scalars + in-wave reduce over the wave's 8 rows ----
        float x = (cg == 0) ? vcur * pq          // -> v^T J q
                : (cg == 1) ? pq * pq            // -> |J q|^2
                : (cg == 2) ? vcur * pu          // -> v^T J u  (A_Jl)
                : 0.f;
        x += __shfl_xor(x, 8);
        x += __shfl_xor(x, 16);
        x += __shfl_xor(x, 32);
        if (lane < 3) wred[w][lane] = x;

        __syncthreads();  // B1

        if (w == 0) {
            float a0 = 0.f, a1 = 0.f, a2 = 0.f;
            if (lane < 16) { a0 = wred[lane][0]; a1 = wred[lane][1]; a2 = wred[lane][2]; }
#pragma unroll
            for (int off = 1; off < 16; off <<= 1) {
                a0 += __shfl_xor(a0, off);
                a1 += __shfl_xor(a1, off);
                a2 += __shfl_xor(a2, off);
            }
            a0 = __shfl(a0, 0); a1 = __shfl(a1, 0); a2 = __shfl(a2, 0);

            const double Jqv = (double)a0;
            const double Jq2 = (double)a1;
            const double AJl = (double)a2;

            // ---- fp64 decision chain (redundant over wave-0 lanes) ----
            trSvv += (double)vvc;
            SJ    += Jqv;
            AJJ   += Jq2;
            const double s_l  = (double)slc;
            const double A_ll = (double)vvc * (double)kqc;
            const bool first = (s == 0);
            const double AJJ_s  = (first || AJJ == 0.0)  ? 1.0 : AJJ;
            const double A_ll_s = (first || A_ll == 0.0) ? 1.0 : A_ll;
            const double denom   = AJJ * A_ll - AJl * AJl;
            const double denom_s = (first || denom == 0.0) ? 1.0 : denom;
            const double rden = 1.0 / denom_s;
            const double wf = (A_ll * SJ - AJl * s_l) * rden;
            const double wi = (AJJ * s_l - AJl * SJ) * rden;
            double wf_c, wi_c;
            if (wi <= 0.0)      { wf_c = SJ / AJJ_s;  wi_c = 0.0; }
            else if (wf <= 0.0) { wf_c = 0.0;         wi_c = s_l / A_ll_s; }
            else                { wf_c = wf;          wi_c = wi; }
            const bool do_update = (s_l * AJJ_s - AJl * SJ) > 0.0;  // margin*AJJ_s

            int mode;
            if (first) {
                mode = 2;
                SJ  = s_l;
                AJJ = A_ll;
            } else if (do_update) {
                mode = 1;
                const double nSJ = wf_c * SJ + wi_c * s_l;
                AJJ = wf_c * wf_c * AJJ + 2.0 * wf_c * wi_c * AJl + wi_c * wi_c * A_ll;
                SJ = nSJ;
            } else {
                mode = 0;
            }

            if (lane == 0) {
                dec[0] = (float)wf_c;
                dec[1] = (float)wi_c;
                dec[2] = (float)mode;
                out[s] = (float)((0.5 * trSvv - SJ + 0.5 * AJJ) * invc);
                out[SEQ + s] = (mode != 0) ? 1.f : 0.f;
            }
        }

        __syncthreads();  // B2

        // ---- J update (pure register ops; decisions via LDS broadcast) ----
        const float md  = dec[2];
        if (md == 2.f) {
            jr0.x = vcur * kk0.x; jr0.y = vcur * kk0.y; jr0.z = vcur * kk0.z; jr0.w = vcur * kk0.w;
            jr1.x = vcur * kk1.x; jr1.y = vcur * kk1.y; jr1.z = vcur * kk1.z; jr1.w = vcur * kk1.w;
            jr2.x = vcur * kk2.x; jr2.y = vcur * kk2.y; jr2.z = vcur * kk2.z; jr2.w = vcur * kk2.w;
            jr3.x = vcur * kk3.x; jr3.y = vcur * kk3.y; jr3.z = vcur * kk3.z; jr3.w = vcur * kk3.w;
        } else if (md == 1.f) {
            const float wff = dec[0];
            const float wvr = dec[1] * vcur;
            jr0.x = fmaf(jr0.x, wff, wvr * kk0.x); jr0.y = fmaf(jr0.y, wff, wvr * kk0.y);
            jr0.z = fmaf(jr0.z, wff, wvr * kk0.z); jr0.w = fmaf(jr0.w, wff, wvr * kk0.w);
            jr1.x = fmaf(jr1.x, wff, wvr * kk1.x); jr1.y = fmaf(jr1.y, wff, wvr * kk1.y);
            jr1.z = fmaf(jr1.z, wff, wvr * kk1.z); jr1.w = fmaf(jr1.w, wff, wvr * kk1.w);
            jr2.x = fmaf(jr2.x, wff, wvr * kk2.x); jr2.y = fmaf(jr2.y, wff, wvr * kk2.y);
            jr2.z = fmaf(jr2.z, wff, wvr * kk2.z); jr2.w = fmaf(jr2.w, wff, wvr * kk2.w);
            jr3.x = fmaf(jr3.x, wff, wvr * kk3.x); jr3.y = fmaf(jr3.y, wff, wvr * kk3.y);
            jr3.z = fmaf(jr3.z, wff, wvr * kk3.z); jr3.w = fmaf(jr3.w, wff, wvr * kk3.w);
        }

        // ---- shifts ----
        vcur = v1; v1 = v2; v2 = vnew;
        slc = sln; kqc = kqn; vvc = vvn; invc = invn;
    }

    // final J (row-major [d_v][d_k]) — coalesced float4 stores
    float* jbase = out + 2 * SEQ + (size_t)r * D + c0;
    *(float4*)(jbase + 0)  = jr0;
    *(float4*)(jbase + 4)  = jr1;
    *(float4*)(jbase + 8)  = jr2;
    *(float4*)(jbase + 12) = jr3;
}

extern "C" void kernel_launch(void* const* d_in, const int* in_sizes, int n_in,
                              void* d_out, int out_size, void* d_ws, size_t ws_size,
                              hipStream_t stream) {
    (void)in_sizes; (void)n_in; (void)out_size; (void)ws_size;
    const float* q = (const float*)d_in[0];
    const float* k = (const float*)d_in[1];
    const float* v = (const float*)d_in[2];
    float* out = (float*)d_out;

    float* U    = (float*)d_ws;             // SEQ*D floats (1 MB)
    float* sl   = U + (size_t)SEQ * D;      // SEQ
    float* kqq  = sl + SEQ;                 // SEQ
    float* vv   = kqq + SEQ;                // SEQ
    double* invl = (double*)(vv + SEQ);     // SEQ doubles (8B-aligned)

    precompute_kernel<<<SEQ, 256, 0, stream>>>(q, k, v, U, sl, kqq, vv, invl);
    scan_kernel<<<1, 1024, 0, stream>>>(q, k, v, U, sl, kqq, vv, invl, out);
}